// Round 1
// baseline (478.226 us; speedup 1.0000x reference)
//
#include <hip/hip_runtime.h>
#include <math.h>

#define M_LFS 20
#define EPS 1e-6f
#define BLOCK 256
#define GRID 2048

__global__ __launch_bounds__(BLOCK) void ratner_nll_kernel(
    const int* __restrict__ L,
    const float* __restrict__ alpha,
    const float* __restrict__ beta,
    float* __restrict__ out,
    int n_rows)
{
    // Per-LF factor tables, computed once per block.
    __shared__ float s_ab[M_LFS];   // abstain  = 1 - beta
    __shared__ float s_ag[M_LFS];   // agree    = beta * a
    __shared__ float s_di[M_LFS];   // disagree = beta * (1 - a)

    const int tid = threadIdx.x;
    if (tid < M_LFS) {
        float al = alpha[tid];
        float b  = beta[tid];
        float a  = 1.0f / (1.0f + __expf(-al));   // sigmoid
        s_ab[tid] = 1.0f - b;
        s_ag[tid] = b * a;
        s_di[tid] = b * (1.0f - a);
    }
    __syncthreads();

    float local = 0.0f;

    const int gid    = blockIdx.x * BLOCK + tid;
    const int stride = gridDim.x * BLOCK;

    for (int row = gid; row < n_rows; row += stride) {
        // Row is 20 int32 = 80 B = 5 x int4, base 16B-aligned (80 % 16 == 0).
        const int4* rp = (const int4*)(L + (size_t)row * M_LFS);
        float pp = 1.0f;  // prod of f_pos
        float pn = 1.0f;  // prod of f_neg
#pragma unroll
        for (int c = 0; c < 5; ++c) {
            int4 v = rp[c];
            int ls0 = v.x, ls1 = v.y, ls2 = v.z, ls3 = v.w;
#pragma unroll
            for (int k = 0; k < 4; ++k) {
                int j = c * 4 + k;
                int l = (k == 0) ? ls0 : (k == 1) ? ls1 : (k == 2) ? ls2 : ls3;
                // wave-uniform shared reads -> broadcast, no bank conflict
                float ab = s_ab[j];
                float ag = s_ag[j];
                float di = s_di[j];
                float fp = (l == 0) ? ab : ((l == 1) ? ag : di);
                float fn = (l == 0) ? ab : ((l == 1) ? di : ag);
                pp *= fp;
                pn *= fn;
            }
        }
        float mu = pp + pn;
        local += __logf(mu + EPS);
    }

    // Wave (64-lane) reduction
#pragma unroll
    for (int off = 32; off > 0; off >>= 1)
        local += __shfl_down(local, off, 64);

    __shared__ float s_wave[BLOCK / 64];
    const int wave = tid >> 6;
    if ((tid & 63) == 0) s_wave[wave] = local;
    __syncthreads();

    if (tid == 0) {
        float bsum = 0.0f;
#pragma unroll
        for (int w = 0; w < BLOCK / 64; ++w) bsum += s_wave[w];
        atomicAdd(out, -bsum);   // nll = -sum(log(mu + eps))
    }
}

extern "C" void kernel_launch(void* const* d_in, const int* in_sizes, int n_in,
                              void* d_out, int out_size, void* d_ws, size_t ws_size,
                              hipStream_t stream) {
    const int*   L     = (const int*)d_in[0];
    const float* alpha = (const float*)d_in[1];
    const float* beta  = (const float*)d_in[2];
    float*       out   = (float*)d_out;

    const int n_rows = in_sizes[0] / M_LFS;

    // d_out is poisoned to 0xAA before every timed launch — zero it (capture-safe).
    hipMemsetAsync(out, 0, sizeof(float), stream);

    ratner_nll_kernel<<<GRID, BLOCK, 0, stream>>>(L, alpha, beta, out, n_rows);
}

// Round 2
// 441.451 us; speedup vs baseline: 1.0833x; 1.0833x over previous
//
#include <hip/hip_runtime.h>
#include <math.h>

#define M_LFS 20
#define EPS 1e-6f
#define BLOCK 256
#define GRID 2048
#define WPB (BLOCK / 64)          // waves per block
#define ROW_PAD 21                // 20 dwords + 1 pad -> odd lane stride, conflict-free LDS reads

__global__ __launch_bounds__(BLOCK) void ratner_nll_kernel(
    const int* __restrict__ L,
    const float* __restrict__ alpha,
    const float* __restrict__ beta,
    float* __restrict__ out,
    int n_rows)
{
    __shared__ float s_ab[M_LFS], s_ag[M_LFS], s_di[M_LFS];
    __shared__ int   s_tile[WPB][64 * ROW_PAD];   // per-wave 64-row staging tile (5376 B/wave)
    __shared__ float s_wred[WPB];

    const int tid  = threadIdx.x;
    const int lane = tid & 63;
    const int wave = tid >> 6;

    if (tid < M_LFS) {
        float a = 1.0f / (1.0f + __expf(-alpha[tid]));   // sigmoid
        float b = beta[tid];
        s_ab[tid] = 1.0f - b;        // abstain
        s_ag[tid] = b * a;           // agree
        s_di[tid] = b * (1.0f - a);  // disagree
    }
    __syncthreads();

    // Wave-uniform tables -> force into SGPRs (keeps VGPR count low)
    float r_ab[M_LFS], r_ag[M_LFS], r_di[M_LFS];
#pragma unroll
    for (int j = 0; j < M_LFS; ++j) {
        r_ab[j] = __int_as_float(__builtin_amdgcn_readfirstlane(__float_as_int(s_ab[j])));
        r_ag[j] = __int_as_float(__builtin_amdgcn_readfirstlane(__float_as_int(s_ag[j])));
        r_di[j] = __int_as_float(__builtin_amdgcn_readfirstlane(__float_as_int(s_di[j])));
    }

    int* tile = &s_tile[wave][0];
    const int4* gp = (const int4*)L;          // L rows: 20 ints = 5 int4, 16B-aligned
    const long  n_i4 = (long)n_rows * 5;

    float local = 0.0f;

    const int n_groups = (n_rows + 63) >> 6;  // 64-row groups
    const int n_waves  = gridDim.x * WPB;

    for (int grp = blockIdx.x * WPB + wave; grp < n_groups; grp += n_waves) {
        const long base = (long)grp * 320;    // group start in int4 units (64 rows * 5)

        // Coalesced stage: 5 contiguous int4 loads/lane, padded LDS writes.
        // Write addr dword idx = 21*(q/5) + 4*(q%5): near-conflict-free (<=2-way typ).
#pragma unroll
        for (int k = 0; k < 5; ++k) {
            const int  q = lane + (k << 6);   // 0..319 within group
            const long g = base + q;
            int4 v = make_int4(0, 0, 0, 0);
            if (g < n_i4) v = gp[g];
            int* dst = tile + (q / 5) * ROW_PAD + (q % 5) * 4;
            dst[0] = v.x; dst[1] = v.y; dst[2] = v.z; dst[3] = v.w;
        }
        // Wave-private tile: only intra-wave visibility needed (in-order LDS pipe).
        __asm__ __volatile__("s_waitcnt lgkmcnt(0)" ::: "memory");

        const int row = (grp << 6) + lane;
        if (row < n_rows) {
            const int* rp = tile + lane * ROW_PAD;  // stride 21 dwords -> 2-way (free)
            float pp = 1.0f, pn = 1.0f;
#pragma unroll
            for (int j = 0; j < M_LFS; ++j) {
                const int   l  = rp[j];
                const float ab = r_ab[j];
                const float fp = (l == 0) ? ab : ((l == 1) ? r_ag[j] : r_di[j]);
                const float fn = (l == 0) ? ab : ((l == 1) ? r_di[j] : r_ag[j]);
                pp *= fp;
                pn *= fn;
            }
            local += __logf(pp + pn + EPS);
        }
        // Keep this iter's reads ordered before next iter's overwrites.
        __asm__ __volatile__("s_waitcnt lgkmcnt(0)" ::: "memory");
    }

    // 64-lane shuffle reduction, then cross-wave via LDS, one atomic per block.
#pragma unroll
    for (int off = 32; off > 0; off >>= 1)
        local += __shfl_down(local, off, 64);
    if (lane == 0) s_wred[wave] = local;
    __syncthreads();
    if (tid == 0) {
        float b = 0.0f;
#pragma unroll
        for (int w = 0; w < WPB; ++w) b += s_wred[w];
        atomicAdd(out, -b);   // nll = -sum(log(mu + eps))
    }
}

extern "C" void kernel_launch(void* const* d_in, const int* in_sizes, int n_in,
                              void* d_out, int out_size, void* d_ws, size_t ws_size,
                              hipStream_t stream) {
    const int*   L     = (const int*)d_in[0];
    const float* alpha = (const float*)d_in[1];
    const float* beta  = (const float*)d_in[2];
    float*       out   = (float*)d_out;

    const int n_rows = in_sizes[0] / M_LFS;

    // d_out is poisoned to 0xAA before every timed launch — zero it (capture-safe).
    hipMemsetAsync(out, 0, sizeof(float), stream);

    ratner_nll_kernel<<<GRID, BLOCK, 0, stream>>>(L, alpha, beta, out, n_rows);
}